// Round 12
// baseline (1301.778 us; speedup 1.0000x reference)
//
#include <hip/hip_runtime.h>
#include <hip/hip_bf16.h>
#include <stdint.h>

typedef unsigned short u16;
typedef unsigned int   u32;
typedef float f32x4  __attribute__((ext_vector_type(4)));
typedef short bf16x8 __attribute__((ext_vector_type(8)));

#define NSEQ 800
#define TOUT 12
#define NC   9
#define LOG2E  1.44269504088896340736f
#define LOG2E2 2.88539008177792681472f

// ---- Round-29: R28 transposed core, register-dieted to fit the 128 wall ----
// R28 (transposed GEMM, h in regs) verified the math but spilled (~150 peak >
// 128 ArchVGPR wall): WRITE 565 MB scratch, 1196 us. R29 cuts ~72 regs:
//  - h state = bf16 packs hp0/hp1 ONLY (hO f32 mirror dropped, -16); blend
//    unpacks prev-h from packs (16 ops/step; bf16-h blend, absmax ~+1e-3).
//  - biases packed bf16 pairs (-32): 32 u32; acc-init unpacks (64 ops/step).
//  - no encoder x-prefetch (-16): x loads are off-chain, issue at loop top.
//  - decoder Lw packed bf16 (-8); output projection accumulated INLINE in the
//    pointwise (p += hn*lw while hn is f32).
// Peak ~119 <= 128. LDS in-loop: 36 loop-invariant W-frag reads, off-chain,
// bank-conflict-free -> pipes can overlap: target max(VALU 530, LDS 450) us.
#define BH_OFF 0
#define BX_OFF 24576
#define LDS_TOTAL 36864

__device__ __forceinline__ u16 f2bf(float f){ union{float f;u32 i;}v; v.f=f; u32 x=v.i; return (u16)((x + 0x7fffu + ((x>>16)&1u))>>16); }
__device__ __forceinline__ u32 pkbf(float a, float b){
  union{ __hip_bfloat162 h2; u32 u; } v;
  v.h2 = __float22bfloat162_rn(float2{a,b});
  return v.u;
}
__device__ __forceinline__ float bflo(u32 u){ union{u32 i;float f;}v; v.i = u<<16; return v.f; }
__device__ __forceinline__ float bfhi(u32 u){ union{u32 i;float f;}v; v.i = u & 0xffff0000u; return v.f; }

union BXU { uint4 u; bf16x8 v; };
union PKU { u32 w[4]; bf16x8 v; };

__global__ __launch_bounds__(512, 1) void rnn_kernel(
  const float* __restrict__ X,
  const float* __restrict__ cw2, const float* __restrict__ cw3, const float* __restrict__ cw4,
  const float* __restrict__ cbv,
  const float* __restrict__ Ewih, const float* __restrict__ Ewhh,
  const float* __restrict__ Ebih, const float* __restrict__ Ebhh,
  const float* __restrict__ Dwih, const float* __restrict__ Dwhh,
  const float* __restrict__ Dbih, const float* __restrict__ Dbhh,
  const float* __restrict__ Lw,   const float* __restrict__ Lb,
  const float* __restrict__ emb,
  float* __restrict__ out)
{
  __shared__ char LDSC[LDS_TOTAL];
  const int tid = threadIdx.x;
  const int wv  = tid >> 6;      // wave id 0..7 -> seq group
  const int l   = tid & 63;
  const int q   = l >> 4;
  const int n   = l & 15;
  const int r   = blockIdx.y;
  const int seqb = blockIdx.x*128 + wv*16;   // this wave's 16 seqs

  const int Kc[NC]={2,2,2,3,3,3,4,4,4};
  const int Dc[NC]={1,2,4,1,2,4,1,2,4};
  const int K = Kc[r], D = Dc[r];
  const int L = 15 - (K-1)*D;

  // ---- whh staging as A-operand (R28-verified transposed j-map) ----
  auto stage_Bh = [&](const float* __restrict__ whh){
    #pragma unroll 1
    for (int it=0; it<3; it++){
      int slot = it*512 + tid;
      int g = slot >> 6, fl = slot & 63;
      int ks = g/12, nt = g%12;
      int col = nt*16 + (fl&15);
      float s = (nt<8) ? LOG2E : LOG2E2;
      u32 w[4] = {0,0,0,0};
      #pragma unroll
      for (int j=0;j<8;j++){
        int hid = ((j&3)<<4) | ((fl>>4)<<2) | (ks<<1) | (j>>2);
        w[j>>1] |= (u32)f2bf(s * whh[col*64 + hid]) << ((j&1)*16);
      }
      *(uint4*)(LDSC + BH_OFF + slot*16) = uint4{w[0],w[1],w[2],w[3]};
    }
  };
  auto stage_Bx_enc = [&](){
    const float* wih = Ewih + r*192*8;
    const float* cw  = (r<3) ? (cw2 + r*128) : (r<6) ? (cw3 + (r-3)*192) : (cw4 + (r-6)*256);
    #pragma unroll 1
    for (int it=0; it<2; it++){
      int slot = it*512 + tid;
      if (slot < 768){
        int g = slot >> 6, fl = slot & 63;
        int col = g*16 + (fl&15);
        int tap = fl>>4;
        float s = (g<8) ? LOG2E : LOG2E2;
        u32 w[4] = {0,0,0,0};
        if (tap < K){
          #pragma unroll
          for (int j=0;j<8;j++){
            float a = 0.f;
            #pragma unroll
            for (int o=0;o<8;o++) a += wih[col*8+o]*cw[(o*8+j)*K + tap];
            w[j>>1] |= (u32)f2bf(s*a) << ((j&1)*16);
          }
        }
        *(uint4*)(LDSC + BX_OFF + slot*16) = uint4{w[0],w[1],w[2],w[3]};
      }
    }
  };
  auto stage_Bx_dec = [&](){
    const float* dwih = Dwih + r*192;
    #pragma unroll 1
    for (int it=0; it<2; it++){
      int slot = it*512 + tid;
      if (slot < 768){
        int g = slot >> 6, fl = slot & 63;
        int col = g*16 + (fl&15);
        float s = (g<8) ? LOG2E : LOG2E2;
        u32 w0 = ((fl>>4)==0) ? (u32)f2bf(s*dwih[col]) : 0u;
        *(uint4*)(LDSC + BX_OFF + slot*16) = uint4{w0,0,0,0};
      }
    }
  };

  stage_Bh(Ewhh + (size_t)r*192*64);
  stage_Bx_enc();

  // ---- biases: q-indexed, packed bf16 pairs (rg 2j,2j+1) -> 32 u32 total ----
  u32 bRp[4][2], bZp[4][2], bNip[4][2], bNhp[4][2];
  {
    const float* bi = Ebih + r*192; const float* bh2 = Ebhh + r*192;
    const float* wih = Ewih + r*192*8; const float* cb = cbv + r*8;
    #pragma unroll
    for (int ht=0; ht<4; ht++){
      float vR[4], vZ[4], vNi[4], vNh[4];
      #pragma unroll
      for (int rg=0; rg<4; rg++){
        int hid = ht*16 + q*4 + rg;
        float cR=0.f,cZ=0.f,cN=0.f;
        #pragma unroll
        for (int o=0;o<8;o++){
          cR += wih[hid*8+o]*cb[o];
          cZ += wih[(64+hid)*8+o]*cb[o];
          cN += wih[(128+hid)*8+o]*cb[o];
        }
        vR[rg]  = LOG2E  * (bi[hid]     + bh2[hid]     + cR);
        vZ[rg]  = LOG2E  * (bi[64+hid]  + bh2[64+hid]  + cZ);
        vNi[rg] = LOG2E2 * (bi[128+hid]                + cN);
        vNh[rg] = LOG2E2 *                bh2[128+hid];
      }
      bRp[ht][0]=pkbf(vR[0],vR[1]);   bRp[ht][1]=pkbf(vR[2],vR[3]);
      bZp[ht][0]=pkbf(vZ[0],vZ[1]);   bZp[ht][1]=pkbf(vZ[2],vZ[3]);
      bNip[ht][0]=pkbf(vNi[0],vNi[1]); bNip[ht][1]=pkbf(vNi[2],vNi[3]);
      bNhp[ht][0]=pkbf(vNh[0],vNh[1]); bNhp[ht][1]=pkbf(vNh[2],vNh[3]);
    }
  }

  // h state: ONLY the packed B-frags. hp0 = seqs' k-slots 0..15, hp1 = 16..31
  PKU hp0, hp1;
  hp0.w[0]=0;hp0.w[1]=0;hp0.w[2]=0;hp0.w[3]=0;
  hp1.w[0]=0;hp1.w[1]=0;hp1.w[2]=0;hp1.w[3]=0;

  // ---- one GRU step (PH = per-element hook for decoder projection) ----
#define PH_NONE(HN,HT,I)
#define PH_DEC(HN,HT,I) do{ u32 lwu = lwp[HT][(I)>>1]; \
    float lwv = ((I)&1)? bfhi(lwu):bflo(lwu); p += (HN)*lwv; }while(0)

#define STEP_CORE(AX, PH) do{ \
    bf16x8 ax_ = (AX); \
    float hsv[4]; u32 pk01[4], pk23[4]; \
    _Pragma("unroll") \
    for (int ht=0; ht<4; ht++){ \
      bf16x8 bR0 = *(const bf16x8*)(LDSC + BH_OFF + ((      ht)*64 + l)*16); \
      bf16x8 bR1 = *(const bf16x8*)(LDSC + BH_OFF + ((12  + ht)*64 + l)*16); \
      bf16x8 bZ0 = *(const bf16x8*)(LDSC + BH_OFF + (( 4 + ht)*64 + l)*16); \
      bf16x8 bZ1 = *(const bf16x8*)(LDSC + BH_OFF + ((16  + ht)*64 + l)*16); \
      bf16x8 bN0 = *(const bf16x8*)(LDSC + BH_OFF + (( 8 + ht)*64 + l)*16); \
      bf16x8 bN1 = *(const bf16x8*)(LDSC + BH_OFF + ((20  + ht)*64 + l)*16); \
      bf16x8 xR  = *(const bf16x8*)(LDSC + BX_OFF + ((      ht)*64 + l)*16); \
      bf16x8 xZ  = *(const bf16x8*)(LDSC + BX_OFF + (( 4 + ht)*64 + l)*16); \
      bf16x8 xN  = *(const bf16x8*)(LDSC + BX_OFF + (( 8 + ht)*64 + l)*16); \
      f32x4 aR  = f32x4{bflo(bRp[ht][0]), bfhi(bRp[ht][0]), bflo(bRp[ht][1]), bfhi(bRp[ht][1])}; \
      f32x4 aZ  = f32x4{bflo(bZp[ht][0]), bfhi(bZp[ht][0]), bflo(bZp[ht][1]), bfhi(bZp[ht][1])}; \
      f32x4 aNi = f32x4{bflo(bNip[ht][0]),bfhi(bNip[ht][0]),bflo(bNip[ht][1]),bfhi(bNip[ht][1])}; \
      f32x4 aNh = f32x4{bflo(bNhp[ht][0]),bfhi(bNhp[ht][0]),bflo(bNhp[ht][1]),bfhi(bNhp[ht][1])}; \
      aR = __builtin_amdgcn_mfma_f32_16x16x32_bf16(bR0, hp0.v, aR,0,0,0); \
      aR = __builtin_amdgcn_mfma_f32_16x16x32_bf16(bR1, hp1.v, aR,0,0,0); \
      aR = __builtin_amdgcn_mfma_f32_16x16x32_bf16(xR,  ax_,   aR,0,0,0); \
      aZ = __builtin_amdgcn_mfma_f32_16x16x32_bf16(bZ0, hp0.v, aZ,0,0,0); \
      aZ = __builtin_amdgcn_mfma_f32_16x16x32_bf16(bZ1, hp1.v, aZ,0,0,0); \
      aZ = __builtin_amdgcn_mfma_f32_16x16x32_bf16(xZ,  ax_,   aZ,0,0,0); \
      aNh= __builtin_amdgcn_mfma_f32_16x16x32_bf16(bN0, hp0.v, aNh,0,0,0); \
      aNh= __builtin_amdgcn_mfma_f32_16x16x32_bf16(bN1, hp1.v, aNh,0,0,0); \
      aNi= __builtin_amdgcn_mfma_f32_16x16x32_bf16(xN,  ax_,   aNi,0,0,0); \
      _Pragma("unroll") \
      for (int i=0;i<4;i++){ \
        float rr = __builtin_amdgcn_rcpf(1.f + __builtin_amdgcn_exp2f(-aR[i])); \
        float zz = __builtin_amdgcn_rcpf(1.f + __builtin_amdgcn_exp2f(-aZ[i])); \
        float y  = aNi[i] + rr*aNh[i]; \
        float nn = 1.f - 2.f*__builtin_amdgcn_rcpf(__builtin_amdgcn_exp2f(y) + 1.f); \
        u32 hw = (i<2) ? hp0.w[((i&1)<<1)|(ht>>1)] : hp1.w[((i&1)<<1)|(ht>>1)]; \
        float hprev = (ht&1) ? bfhi(hw) : bflo(hw); \
        float hn = nn + zz*(hprev - nn); \
        PH(hn, ht, i); \
        if (ht==0)      hsv[i] = hn; \
        else if (ht==1) pk01[i] = pkbf(hsv[i], hn); \
        else if (ht==2) hsv[i] = hn; \
        else            pk23[i] = pkbf(hsv[i], hn); \
      } \
    } \
    hp0.w[0]=pk01[0]; hp0.w[1]=pk23[0]; hp0.w[2]=pk01[1]; hp0.w[3]=pk23[1]; \
    hp1.w[0]=pk01[2]; hp1.w[1]=pk23[2]; hp1.w[2]=pk01[3]; hp1.w[3]=pk23[3]; \
  }while(0)

  // ---------- encoder: NO barriers, no prefetch (x loads are off-chain) ----------
  const float* xb = X + (size_t)(seqb + n)*120 + ((q<K)? q:0)*D*8;
  __syncthreads();   // staging visible
  #pragma unroll 1
  for (int t=0; t<L; t++){
    float4 v0 = *(const float4*)(xb + t*8);
    float4 v1 = *(const float4*)(xb + t*8 + 4);
    BXU a;
    a.u.x = __builtin_amdgcn_perm(__float_as_uint(v0.y), __float_as_uint(v0.x), 0x07060302u);
    a.u.y = __builtin_amdgcn_perm(__float_as_uint(v0.w), __float_as_uint(v0.z), 0x07060302u);
    a.u.z = __builtin_amdgcn_perm(__float_as_uint(v1.y), __float_as_uint(v1.x), 0x07060302u);
    a.u.w = __builtin_amdgcn_perm(__float_as_uint(v1.w), __float_as_uint(v1.z), 0x07060302u);
    STEP_CORE(a.v, PH_NONE);
  }

  // ---------- decoder weight switch (2 barriers around restage) ----------
  __syncthreads();
  stage_Bh(Dwhh + (size_t)r*192*64);
  stage_Bx_dec();
  {
    const float* bi = Dbih + r*192; const float* bh2 = Dbhh + r*192;
    #pragma unroll
    for (int ht=0; ht<4; ht++){
      float vR[4], vZ[4], vNi[4], vNh[4];
      #pragma unroll
      for (int rg=0; rg<4; rg++){
        int hid = ht*16 + q*4 + rg;
        vR[rg]  = LOG2E  * (bi[hid]     + bh2[hid]);
        vZ[rg]  = LOG2E  * (bi[64+hid]  + bh2[64+hid]);
        vNi[rg] = LOG2E2 *  bi[128+hid];
        vNh[rg] = LOG2E2 *  bh2[128+hid];
      }
      bRp[ht][0]=pkbf(vR[0],vR[1]);   bRp[ht][1]=pkbf(vR[2],vR[3]);
      bZp[ht][0]=pkbf(vZ[0],vZ[1]);   bZp[ht][1]=pkbf(vZ[2],vZ[3]);
      bNip[ht][0]=pkbf(vNi[0],vNi[1]); bNip[ht][1]=pkbf(vNi[2],vNi[3]);
      bNhp[ht][0]=pkbf(vNh[0],vNh[1]); bNhp[ht][1]=pkbf(vNh[2],vNh[3]);
    }
  }
  u32 lwp[4][2];
  #pragma unroll
  for (int ht=0; ht<4; ht++){
    lwp[ht][0] = pkbf(Lw[r*64 + ht*16 + q*4 + 0], Lw[r*64 + ht*16 + q*4 + 1]);
    lwp[ht][1] = pkbf(Lw[r*64 + ht*16 + q*4 + 2], Lw[r*64 + ht*16 + q*4 + 3]);
  }
  const float lb_ = Lb[r];
  float wgt;
  {
    int nb = (seqb + n) % NSEQ;
    float e[NC], mx = -1e30f;
    #pragma unroll
    for (int c=0;c<NC;c++){ e[c] = emb[nb*NC+c]; mx = fmaxf(mx, e[c]); }
    float sm = 0.f;
    #pragma unroll
    for (int c=0;c<NC;c++) sm += __expf(e[c]-mx);
    wgt = __expf(e[r]-mx) / sm;
  }
  float lv = X[(size_t)(seqb + n)*120 + 112];   // last0 for seq n
  __syncthreads();   // dec staging visible

  // ---------- decoder: lv lane-local; projection accumulated inline ----------
  #pragma unroll 1
  for (int t=0; t<TOUT; t++){
    BXU a; a.u = uint4{0,0,0,0};
    if (q==0) a.u.x = (u32)f2bf(lv);   // B[k=0][seq n] = lv
    float p = 0.f;
    STEP_CORE(a.v, PH_DEC);
    p += __shfl_xor(p, 16, 64);
    p += __shfl_xor(p, 32, 64);
    float v = p + lb_;
    lv = v;
    if (q==0) atomicAdd(out + (size_t)(seqb+n)*TOUT + t, wgt*v);
  }
}

extern "C" void kernel_launch(void* const* d_in, const int* in_sizes, int n_in,
                              void* d_out, int out_size, void* d_ws, size_t ws_size,
                              hipStream_t stream)
{
  float* out = (float*)d_out;
  hipMemsetAsync(out, 0, (size_t)out_size*sizeof(float), stream);

  dim3 g(NSEQ*64/128, NC);   // 400 x 9 blocks; 128 seqs/block, 8 seq-split waves
  rnn_kernel<<<g, 512, 0, stream>>>(
    (const float*)d_in[1],
    (const float*)d_in[2], (const float*)d_in[3], (const float*)d_in[4],
    (const float*)d_in[5],
    (const float*)d_in[6], (const float*)d_in[7], (const float*)d_in[8], (const float*)d_in[9],
    (const float*)d_in[10],(const float*)d_in[11],(const float*)d_in[12],(const float*)d_in[13],
    (const float*)d_in[14],(const float*)d_in[15],
    (const float*)d_in[16],
    out);
}

// Round 13
// 757.741 us; speedup vs baseline: 1.7180x; 1.7180x over previous
//
#include <hip/hip_runtime.h>
#include <hip/hip_bf16.h>
#include <stdint.h>

typedef unsigned short u16;
typedef unsigned int   u32;
typedef float f32x4  __attribute__((ext_vector_type(4)));
typedef short bf16x8 __attribute__((ext_vector_type(8)));

#define NSEQ 800
#define TOUT 12
#define NC   9
#define LOG2E  1.44269504088896340736f
#define LOG2E2 2.88539008177792681472f

// ---- Round-30: R25 hot loop + precomputed staging (prep kernel into d_ws) ----
// R28/R29 transposed line abandoned (can't fit 128 ArchVGPR; scratch every try).
// R25 (924 us) re-audited: WRITE 172.8MB == atomic RMW traffic exactly -> ZERO
// spill; clean. Remaining attackable cost: per-block staging (scattered scalar
// loads + f2bf + conv-fold + bias math, x7200 blocks) + mid-kernel barrier pair.
// R30: prep kernel (9 blocks, ~8us) writes final LDS images (enc+dec Bh/Bx,
// R25-verified maps), bias vectors, softmax wgts into d_ws. Main kernel stages
// by coalesced uint4 copy (9 iters), BOTH enc+dec images up-front (LDS 90112,
// still 1 block/CU - register-locked anyway), ONE barrier total; mid-kernel
// restage+barriers deleted. Hot loop byte-identical to R25.
// ws layout: [r]*73728: BHE@0 BXE@24576 BHD@36864 BXD@61440 (73728B x 9)
//            BIASE@663552 [r][n][16]f32 ; BIASD@672768 ; WGT@681984 [nb][9]f32
#define WIMG_STRIDE 73728
#define LDS_BHE 0
#define LDS_BXE 24576
#define LDS_BHD 36864
#define LDS_BXD 61440
#define LDS_H   73728
#define LDS_TOTAL 90112
#define BIASE_OFF 663552
#define BIASD_OFF 672768
#define WGT_OFF   681984

__device__ __forceinline__ u16 f2bf(float f){ union{float f;u32 i;}v; v.f=f; u32 x=v.i; return (u16)((x + 0x7fffu + ((x>>16)&1u))>>16); }
__device__ __forceinline__ u32 pkbf(float a, float b){
  union{ __hip_bfloat162 h2; u32 u; } v;
  v.h2 = __float22bfloat162_rn(float2{a,b});
  return v.u;
}

union BXU { uint4 u; bf16x8 v; };

// ================= prep kernel: build LDS images + biases + softmax ==========
__global__ void prep_kernel(
  const float* __restrict__ cw2, const float* __restrict__ cw3, const float* __restrict__ cw4,
  const float* __restrict__ cbv,
  const float* __restrict__ Ewih, const float* __restrict__ Ewhh,
  const float* __restrict__ Ebih, const float* __restrict__ Ebhh,
  const float* __restrict__ Dwih, const float* __restrict__ Dwhh,
  const float* __restrict__ Dbih, const float* __restrict__ Dbhh,
  const float* __restrict__ emb,
  char* __restrict__ ws)
{
  const int r = blockIdx.x;
  const int tid = threadIdx.x;
  const int K = (r<3) ? 2 : ((r<6) ? 3 : 4);
  char* wimg = ws + (size_t)r*WIMG_STRIDE;

  // whh images (enc + dec), R25 B-operand map
  const float* ewhh = Ewhh + (size_t)r*192*64;
  const float* dwhh = Dwhh + (size_t)r*192*64;
  #pragma unroll 1
  for (int s = tid; s < 1536; s += 512){
    int g = s >> 6, fl = s & 63;
    int ks = g/12, nt = g%12;
    int col = nt*16 + (fl&15);
    float sc = (nt<8) ? LOG2E : LOG2E2;
    u32 we[4] = {0,0,0,0}, wd[4] = {0,0,0,0};
    #pragma unroll
    for (int j=0;j<8;j++){
      int hid = ((j&3)<<4) | (ks*8 + (fl>>4)*2 + (j>>2));
      we[j>>1] |= (u32)f2bf(sc * ewhh[col*64 + hid]) << ((j&1)*16);
      wd[j>>1] |= (u32)f2bf(sc * dwhh[col*64 + hid]) << ((j&1)*16);
    }
    *(uint4*)(wimg + LDS_BHE + s*16) = uint4{we[0],we[1],we[2],we[3]};
    *(uint4*)(wimg + LDS_BHD + s*16) = uint4{wd[0],wd[1],wd[2],wd[3]};
  }
  // x-weight images (enc conv-folded, dec scalar column)
  const float* wih = Ewih + r*192*8;
  const float* cw  = (r<3) ? (cw2 + r*128) : (r<6) ? (cw3 + (r-3)*192) : (cw4 + (r-6)*256);
  const float* dwih = Dwih + r*192;
  #pragma unroll 1
  for (int s = tid; s < 768; s += 512){
    int g = s >> 6, fl = s & 63;
    int col = g*16 + (fl&15);
    int tap = fl>>4;
    float sc = (g<8) ? LOG2E : LOG2E2;
    u32 w[4] = {0,0,0,0};
    if (tap < K){
      #pragma unroll
      for (int j=0;j<8;j++){
        float a = 0.f;
        #pragma unroll
        for (int o=0;o<8;o++) a += wih[col*8+o]*cw[(o*8+j)*K + tap];
        w[j>>1] |= (u32)f2bf(sc*a) << ((j&1)*16);
      }
    }
    *(uint4*)(wimg + LDS_BXE + s*16) = uint4{w[0],w[1],w[2],w[3]};
    u32 w0 = (tap==0) ? (u32)f2bf(sc*dwih[col]) : 0u;
    *(uint4*)(wimg + LDS_BXD + s*16) = uint4{w0,0,0,0};
  }
  // biases: [r][n][ g*4+ht ], g in {R,Z,Ni,Nh}
  if (tid < 16){
    int n = tid;
    const float* bi = Ebih + r*192; const float* bh2 = Ebhh + r*192;
    const float* cb = cbv + r*8;
    float* be = (float*)(ws + BIASE_OFF) + ((size_t)r*16 + n)*16;
    #pragma unroll
    for (int ht=0; ht<4; ht++){
      int hid = ht*16 + n;
      float cR=0.f,cZ=0.f,cN=0.f;
      #pragma unroll
      for (int o=0;o<8;o++){
        cR += wih[hid*8+o]*cb[o];
        cZ += wih[(64+hid)*8+o]*cb[o];
        cN += wih[(128+hid)*8+o]*cb[o];
      }
      be[ht]    = LOG2E  * (bi[hid]     + bh2[hid]     + cR);
      be[4+ht]  = LOG2E  * (bi[64+hid]  + bh2[64+hid]  + cZ);
      be[8+ht]  = LOG2E2 * (bi[128+hid]                + cN);
      be[12+ht] = LOG2E2 *                bh2[128+hid];
    }
  } else if (tid < 32){
    int n = tid - 16;
    const float* bi = Dbih + r*192; const float* bh2 = Dbhh + r*192;
    float* bd = (float*)(ws + BIASD_OFF) + ((size_t)r*16 + n)*16;
    #pragma unroll
    for (int ht=0; ht<4; ht++){
      int hid = ht*16 + n;
      bd[ht]    = LOG2E  * (bi[hid]     + bh2[hid]);
      bd[4+ht]  = LOG2E  * (bi[64+hid]  + bh2[64+hid]);
      bd[8+ht]  = LOG2E2 *  bi[128+hid];
      bd[12+ht] = LOG2E2 *  bh2[128+hid];
    }
  }
  // softmax weights [nb][9]
  if (r == 0){
    float* wg = (float*)(ws + WGT_OFF);
    #pragma unroll 1
    for (int nb = tid; nb < NSEQ; nb += 512){
      float e[NC], mx = -1e30f;
      #pragma unroll
      for (int c=0;c<NC;c++){ e[c] = emb[nb*NC+c]; mx = fmaxf(mx, e[c]); }
      float sm = 0.f;
      #pragma unroll
      for (int c=0;c<NC;c++){ e[c] = __expf(e[c]-mx); sm += e[c]; }
      float inv = 1.f/sm;
      #pragma unroll
      for (int c=0;c<NC;c++) wg[nb*NC+c] = e[c]*inv;
    }
  }
}

// ================= main kernel: R25 hot loop, copy-staged, 1 barrier =========
__global__ __launch_bounds__(512, 2) void rnn_kernel(
  const float* __restrict__ X,
  const float* __restrict__ Lw, const float* __restrict__ Lb,
  const char* __restrict__ ws,
  float* __restrict__ out)
{
  __shared__ char LDSC[LDS_TOTAL];
  const int tid = threadIdx.x;
  const int wv  = tid >> 6;
  const int l   = tid & 63;
  const int q   = l >> 4;
  const int n   = l & 15;
  const int r   = blockIdx.y;
  const int seqb = blockIdx.x*128 + wv*16;

  const int Kc[NC]={2,2,2,3,3,3,4,4,4};
  const int Dc[NC]={1,2,4,1,2,4,1,2,4};
  const int K = Kc[r], D = Dc[r];
  const int L = 15 - (K-1)*D;

  // zero own h slice (wave-private)
  const int HB = LDS_H + wv*2048;
  *(uint4*)(LDSC + HB + l*32)      = uint4{0,0,0,0};
  *(uint4*)(LDSC + HB + l*32 + 16) = uint4{0,0,0,0};

  // coalesced copy of all 4 weight images (4608 uint4 = 9 x 512)
  {
    const uint4* src = (const uint4*)(ws + (size_t)r*WIMG_STRIDE);
    #pragma unroll 1
    for (int it=0; it<9; it++){
      int idx = it*512 + tid;
      *(uint4*)(LDSC + idx*16) = src[idx];
    }
  }

  // encoder biases from ws
  float bR4[4], bZ4[4], bNi4[4], bNh4[4];
  {
    const float* be = (const float*)(ws + BIASE_OFF) + ((size_t)r*16 + n)*16;
    float4 v0 = *(const float4*)(be);
    float4 v1 = *(const float4*)(be+4);
    float4 v2 = *(const float4*)(be+8);
    float4 v3 = *(const float4*)(be+12);
    bR4[0]=v0.x; bR4[1]=v0.y; bR4[2]=v0.z; bR4[3]=v0.w;
    bZ4[0]=v1.x; bZ4[1]=v1.y; bZ4[2]=v1.z; bZ4[3]=v1.w;
    bNi4[0]=v2.x; bNi4[1]=v2.y; bNi4[2]=v2.z; bNi4[3]=v2.w;
    bNh4[0]=v3.x; bNh4[1]=v3.y; bNh4[2]=v3.z; bNh4[3]=v3.w;
  }

  float hO[4][4];
  #pragma unroll
  for (int ht=0;ht<4;ht++) for (int i=0;i<4;i++) hO[ht][i]=0.f;

  // step-invariant h addresses
  const int ra0 = HB + n*128 + (((  q + n)&7)<<4);
  const int ra1 = HB + n*128 + (((4+q + n)&7)<<4);
  int wa[4];
  #pragma unroll
  for (int i=0;i<4;i++){
    int seq = q*4+i;
    wa[i] = HB + seq*128 + ((((n>>1) + seq)&7)<<4) + ((n&1)<<3);
  }

  // ---- one GRU step (R25-identical), parametrized by weight-image offsets ----
  auto step_core = [&](int bho, int bxo, bf16x8 ax){
    bf16x8 a0 = *(const bf16x8*)(LDSC + ra0);
    bf16x8 a1 = *(const bf16x8*)(LDSC + ra1);
    float hsv[4]; u32 pk01[4], pk23[4];
    #pragma unroll
    for (int ht=0; ht<4; ht++){
      bf16x8 bR0 = *(const bf16x8*)(LDSC + bho + ((      ht)*64 + l)*16);
      bf16x8 bR1 = *(const bf16x8*)(LDSC + bho + ((12  + ht)*64 + l)*16);
      bf16x8 bZ0 = *(const bf16x8*)(LDSC + bho + (( 4 + ht)*64 + l)*16);
      bf16x8 bZ1 = *(const bf16x8*)(LDSC + bho + ((16  + ht)*64 + l)*16);
      bf16x8 bN0 = *(const bf16x8*)(LDSC + bho + (( 8 + ht)*64 + l)*16);
      bf16x8 bN1 = *(const bf16x8*)(LDSC + bho + ((20  + ht)*64 + l)*16);
      bf16x8 xR  = *(const bf16x8*)(LDSC + bxo + ((      ht)*64 + l)*16);
      bf16x8 xZ  = *(const bf16x8*)(LDSC + bxo + (( 4 + ht)*64 + l)*16);
      bf16x8 xN  = *(const bf16x8*)(LDSC + bxo + (( 8 + ht)*64 + l)*16);
      f32x4 aR  = f32x4{bR4[ht],bR4[ht],bR4[ht],bR4[ht]};
      f32x4 aZ  = f32x4{bZ4[ht],bZ4[ht],bZ4[ht],bZ4[ht]};
      f32x4 aNi = f32x4{bNi4[ht],bNi4[ht],bNi4[ht],bNi4[ht]};
      f32x4 aNh = f32x4{bNh4[ht],bNh4[ht],bNh4[ht],bNh4[ht]};
      aR = __builtin_amdgcn_mfma_f32_16x16x32_bf16(a0, bR0, aR,0,0,0);
      aR = __builtin_amdgcn_mfma_f32_16x16x32_bf16(a1, bR1, aR,0,0,0);
      aR = __builtin_amdgcn_mfma_f32_16x16x32_bf16(ax, xR,  aR,0,0,0);
      aZ = __builtin_amdgcn_mfma_f32_16x16x32_bf16(a0, bZ0, aZ,0,0,0);
      aZ = __builtin_amdgcn_mfma_f32_16x16x32_bf16(a1, bZ1, aZ,0,0,0);
      aZ = __builtin_amdgcn_mfma_f32_16x16x32_bf16(ax, xZ,  aZ,0,0,0);
      aNh= __builtin_amdgcn_mfma_f32_16x16x32_bf16(a0, bN0, aNh,0,0,0);
      aNh= __builtin_amdgcn_mfma_f32_16x16x32_bf16(a1, bN1, aNh,0,0,0);
      aNi= __builtin_amdgcn_mfma_f32_16x16x32_bf16(ax, xN,  aNi,0,0,0);
      #pragma unroll
      for (int i=0;i<4;i++){
        float rr = __builtin_amdgcn_rcpf(1.f + __builtin_amdgcn_exp2f(-aR[i]));
        float zz = __builtin_amdgcn_rcpf(1.f + __builtin_amdgcn_exp2f(-aZ[i]));
        float y  = aNi[i] + rr*aNh[i];
        float nn = 1.f - 2.f*__builtin_amdgcn_rcpf(__builtin_amdgcn_exp2f(y) + 1.f);
        float hn = nn + zz*(hO[ht][i]-nn);
        hO[ht][i] = hn;
        if (ht==0)      hsv[i] = hn;
        else if (ht==1) pk01[i] = pkbf(hsv[i], hn);
        else if (ht==2) hsv[i] = hn;
        else            pk23[i] = pkbf(hsv[i], hn);
      }
    }
    #pragma unroll
    for (int i=0;i<4;i++){
      uint2 wv2; wv2.x = pk01[i]; wv2.y = pk23[i];
      *(uint2*)(LDSC + wa[i]) = wv2;
    }
  };

  // ---------- encoder: NO barriers in loop; x prefetched one step ahead ------
  const float* xb = X + (size_t)(seqb + n)*120 + ((q<K)? q:0)*D*8;
  float4 c0 = *(const float4*)(xb);
  float4 c1 = *(const float4*)(xb + 4);
  __syncthreads();   // the ONLY barrier: staging copy visible
  #pragma unroll 1
  for (int t=0; t<L; t++){
    int tn = (t+1 < L) ? (t+1) : t;
    float4 n0 = *(const float4*)(xb + tn*8);
    float4 n1 = *(const float4*)(xb + tn*8 + 4);
    BXU a;
    a.u.x = __builtin_amdgcn_perm(__float_as_uint(c0.y), __float_as_uint(c0.x), 0x07060302u);
    a.u.y = __builtin_amdgcn_perm(__float_as_uint(c0.w), __float_as_uint(c0.z), 0x07060302u);
    a.u.z = __builtin_amdgcn_perm(__float_as_uint(c1.y), __float_as_uint(c1.x), 0x07060302u);
    a.u.w = __builtin_amdgcn_perm(__float_as_uint(c1.w), __float_as_uint(c1.z), 0x07060302u);
    step_core(LDS_BHE, LDS_BXE, a.v);
    c0 = n0; c1 = n1;
  }

  // ---------- decoder switch: NO barriers (images pre-staged) ----------
  {
    const float* bd = (const float*)(ws + BIASD_OFF) + ((size_t)r*16 + n)*16;
    float4 v0 = *(const float4*)(bd);
    float4 v1 = *(const float4*)(bd+4);
    float4 v2 = *(const float4*)(bd+8);
    float4 v3 = *(const float4*)(bd+12);
    bR4[0]=v0.x; bR4[1]=v0.y; bR4[2]=v0.z; bR4[3]=v0.w;
    bZ4[0]=v1.x; bZ4[1]=v1.y; bZ4[2]=v1.z; bZ4[3]=v1.w;
    bNi4[0]=v2.x; bNi4[1]=v2.y; bNi4[2]=v2.z; bNi4[3]=v2.w;
    bNh4[0]=v3.x; bNh4[1]=v3.y; bNh4[2]=v3.z; bNh4[3]=v3.w;
  }
  float lwr[4];
  #pragma unroll
  for (int ht=0; ht<4; ht++) lwr[ht] = Lw[r*64 + ht*16 + n];
  const float lb_ = Lb[r];
  const float wgt = ((const float*)(ws + WGT_OFF))[((seqb + n) % NSEQ)*NC + r];
  float lv = X[(size_t)(seqb + n)*120 + 112];

  // ---------- decoder: NO barriers in loop (wave-local reduce) ----------
  #pragma unroll 1
  for (int t=0; t<TOUT; t++){
    BXU a; a.u = uint4{0,0,0,0};
    if (q==0) a.u.x = (u32)f2bf(lv);
    step_core(LDS_BHD, LDS_BXD, a.v);
    float p[4];
    #pragma unroll
    for (int i=0;i<4;i++)
      p[i] = hO[0][i]*lwr[0] + hO[1][i]*lwr[1] + hO[2][i]*lwr[2] + hO[3][i]*lwr[3];
    #pragma unroll
    for (int m=1; m<16; m<<=1){
      #pragma unroll
      for (int i=0;i<4;i++) p[i] += __shfl_xor(p[i], m, 64);
    }
    float s0 = (n&2) ? p[2] : p[0];
    float s1 = (n&2) ? p[3] : p[1];
    float se = (n&1) ? s1 : s0;
    float v = __shfl(se, (n>>2)*16 + (n&3), 64) + lb_;
    lv = v;
    if (q==0) atomicAdd(out + (size_t)(seqb+n)*TOUT + t, wgt*v);
  }
}

extern "C" void kernel_launch(void* const* d_in, const int* in_sizes, int n_in,
                              void* d_out, int out_size, void* d_ws, size_t ws_size,
                              hipStream_t stream)
{
  float* out = (float*)d_out;
  hipMemsetAsync(out, 0, (size_t)out_size*sizeof(float), stream);

  prep_kernel<<<dim3(NC), 512, 0, stream>>>(
    (const float*)d_in[2], (const float*)d_in[3], (const float*)d_in[4],
    (const float*)d_in[5],
    (const float*)d_in[6], (const float*)d_in[7], (const float*)d_in[8], (const float*)d_in[9],
    (const float*)d_in[10],(const float*)d_in[11],(const float*)d_in[12],(const float*)d_in[13],
    (const float*)d_in[16],
    (char*)d_ws);

  dim3 g(NSEQ*64/128, NC);   // 400 x 9 blocks; 128 seqs/block, 8 seq-split waves
  rnn_kernel<<<g, 512, 0, stream>>>(
    (const float*)d_in[1],
    (const float*)d_in[14], (const float*)d_in[15],
    (const char*)d_ws,
    out);
}

// Round 14
// 745.617 us; speedup vs baseline: 1.7459x; 1.0163x over previous
//
#include <hip/hip_runtime.h>
#include <hip/hip_bf16.h>
#include <stdint.h>

typedef unsigned short u16;
typedef unsigned int   u32;
typedef float f32x4  __attribute__((ext_vector_type(4)));
typedef short bf16x8 __attribute__((ext_vector_type(8)));

#define NSEQ 800
#define TOUT 12
#define NC   9
#define LOG2E  1.44269504088896340736f
#define LOG2E2 2.88539008177792681472f

// ---- Round-31: R30 base + scalar decoder (R27 math) + fused blend/tanh ----
// R30 (758 us) pipe audit: LDS pipe per CU = 8 waves x 38 ds_read_b128 x 12cy
// ~= 477 us (the binding pipe); VALU ~450; MFMA 136; observed 740 = partial
// overlap. Occupancy register-locked at 1 block/CU (12 rounds) — not a lever.
// R31 cuts LDS demand: decoder (54% of steps) x-path collapses to acc-init
// fmas (R27-verified): dec 38->26 reads => LDS 477->~395. BXD dropped from
// LDS (77824 B). And cuts VALU: fused z-blend+tanh
//   hn = [En(Ez+h)+(h-Ez)] / [(En+1)(Ez+1)],  En=exp2(y), Ez=exp2(-aZ)
// -> 5 trans/elem instead of 6 (-96 cy/step).
// ws layout unchanged from R30 (prep writes BXD; main just doesn't copy it).
#define WIMG_STRIDE 73728
#define LDS_BHE 0
#define LDS_BXE 24576
#define LDS_BHD 36864
#define LDS_H   61440
#define LDS_TOTAL 77824
#define BIASE_OFF 663552
#define BIASD_OFF 672768
#define WGT_OFF   681984

__device__ __forceinline__ u16 f2bf(float f){ union{float f;u32 i;}v; v.f=f; u32 x=v.i; return (u16)((x + 0x7fffu + ((x>>16)&1u))>>16); }
__device__ __forceinline__ u32 pkbf(float a, float b){
  union{ __hip_bfloat162 h2; u32 u; } v;
  v.h2 = __float22bfloat162_rn(float2{a,b});
  return v.u;
}

union BXU { uint4 u; bf16x8 v; };

// ================= prep kernel: build LDS images + biases + softmax ==========
__global__ void prep_kernel(
  const float* __restrict__ cw2, const float* __restrict__ cw3, const float* __restrict__ cw4,
  const float* __restrict__ cbv,
  const float* __restrict__ Ewih, const float* __restrict__ Ewhh,
  const float* __restrict__ Ebih, const float* __restrict__ Ebhh,
  const float* __restrict__ Dwih, const float* __restrict__ Dwhh,
  const float* __restrict__ Dbih, const float* __restrict__ Dbhh,
  const float* __restrict__ emb,
  char* __restrict__ ws)
{
  const int r = blockIdx.x;
  const int tid = threadIdx.x;
  const int K = (r<3) ? 2 : ((r<6) ? 3 : 4);
  char* wimg = ws + (size_t)r*WIMG_STRIDE;

  const float* ewhh = Ewhh + (size_t)r*192*64;
  const float* dwhh = Dwhh + (size_t)r*192*64;
  #pragma unroll 1
  for (int s = tid; s < 1536; s += 512){
    int g = s >> 6, fl = s & 63;
    int ks = g/12, nt = g%12;
    int col = nt*16 + (fl&15);
    float sc = (nt<8) ? LOG2E : LOG2E2;
    u32 we[4] = {0,0,0,0}, wd[4] = {0,0,0,0};
    #pragma unroll
    for (int j=0;j<8;j++){
      int hid = ((j&3)<<4) | (ks*8 + (fl>>4)*2 + (j>>2));
      we[j>>1] |= (u32)f2bf(sc * ewhh[col*64 + hid]) << ((j&1)*16);
      wd[j>>1] |= (u32)f2bf(sc * dwhh[col*64 + hid]) << ((j&1)*16);
    }
    *(uint4*)(wimg + LDS_BHE + s*16) = uint4{we[0],we[1],we[2],we[3]};
    *(uint4*)(wimg + LDS_BHD + s*16) = uint4{wd[0],wd[1],wd[2],wd[3]};
  }
  const float* wih = Ewih + r*192*8;
  const float* cw  = (r<3) ? (cw2 + r*128) : (r<6) ? (cw3 + (r-3)*192) : (cw4 + (r-6)*256);
  #pragma unroll 1
  for (int s = tid; s < 768; s += 512){
    int g = s >> 6, fl = s & 63;
    int col = g*16 + (fl&15);
    int tap = fl>>4;
    float sc = (g<8) ? LOG2E : LOG2E2;
    u32 w[4] = {0,0,0,0};
    if (tap < K){
      #pragma unroll
      for (int j=0;j<8;j++){
        float a = 0.f;
        #pragma unroll
        for (int o=0;o<8;o++) a += wih[col*8+o]*cw[(o*8+j)*K + tap];
        w[j>>1] |= (u32)f2bf(sc*a) << ((j&1)*16);
      }
    }
    *(uint4*)(wimg + LDS_BXE + s*16) = uint4{w[0],w[1],w[2],w[3]};
  }
  if (tid < 16){
    int n = tid;
    const float* bi = Ebih + r*192; const float* bh2 = Ebhh + r*192;
    const float* cb = cbv + r*8;
    float* be = (float*)(ws + BIASE_OFF) + ((size_t)r*16 + n)*16;
    #pragma unroll
    for (int ht=0; ht<4; ht++){
      int hid = ht*16 + n;
      float cR=0.f,cZ=0.f,cN=0.f;
      #pragma unroll
      for (int o=0;o<8;o++){
        cR += wih[hid*8+o]*cb[o];
        cZ += wih[(64+hid)*8+o]*cb[o];
        cN += wih[(128+hid)*8+o]*cb[o];
      }
      be[ht]    = LOG2E  * (bi[hid]     + bh2[hid]     + cR);
      be[4+ht]  = LOG2E  * (bi[64+hid]  + bh2[64+hid]  + cZ);
      be[8+ht]  = LOG2E2 * (bi[128+hid]                + cN);
      be[12+ht] = LOG2E2 *                bh2[128+hid];
    }
  } else if (tid < 32){
    int n = tid - 16;
    const float* bi = Dbih + r*192; const float* bh2 = Dbhh + r*192;
    float* bd = (float*)(ws + BIASD_OFF) + ((size_t)r*16 + n)*16;
    #pragma unroll
    for (int ht=0; ht<4; ht++){
      int hid = ht*16 + n;
      bd[ht]    = LOG2E  * (bi[hid]     + bh2[hid]);
      bd[4+ht]  = LOG2E  * (bi[64+hid]  + bh2[64+hid]);
      bd[8+ht]  = LOG2E2 *  bi[128+hid];
      bd[12+ht] = LOG2E2 *  bh2[128+hid];
    }
  }
  if (r == 0){
    float* wg = (float*)(ws + WGT_OFF);
    #pragma unroll 1
    for (int nb = tid; nb < NSEQ; nb += 512){
      float e[NC], mx = -1e30f;
      #pragma unroll
      for (int c=0;c<NC;c++){ e[c] = emb[nb*NC+c]; mx = fmaxf(mx, e[c]); }
      float sm = 0.f;
      #pragma unroll
      for (int c=0;c<NC;c++){ e[c] = __expf(e[c]-mx); sm += e[c]; }
      float inv = 1.f/sm;
      #pragma unroll
      for (int c=0;c<NC;c++) wg[nb*NC+c] = e[c]*inv;
    }
  }
}

// ================= main kernel ==============================================
__global__ __launch_bounds__(512, 2) void rnn_kernel(
  const float* __restrict__ X,
  const float* __restrict__ Dwih,
  const float* __restrict__ Lw, const float* __restrict__ Lb,
  const char* __restrict__ ws,
  float* __restrict__ out)
{
  __shared__ char LDSC[LDS_TOTAL];
  const int tid = threadIdx.x;
  const int wv  = tid >> 6;
  const int l   = tid & 63;
  const int q   = l >> 4;
  const int n   = l & 15;
  const int r   = blockIdx.y;
  const int seqb = blockIdx.x*128 + wv*16;

  const int Kc[NC]={2,2,2,3,3,3,4,4,4};
  const int Dc[NC]={1,2,4,1,2,4,1,2,4};
  const int K = Kc[r], D = Dc[r];
  const int L = 15 - (K-1)*D;

  // zero own h slice (wave-private)
  const int HB = LDS_H + wv*2048;
  *(uint4*)(LDSC + HB + l*32)      = uint4{0,0,0,0};
  *(uint4*)(LDSC + HB + l*32 + 16) = uint4{0,0,0,0};

  // coalesced copy of BHE+BXE+BHD (3840 uint4)
  {
    const uint4* src = (const uint4*)(ws + (size_t)r*WIMG_STRIDE);
    #pragma unroll 1
    for (int it=0; it<8; it++){
      int idx = it*512 + tid;
      if (idx < 3840) *(uint4*)(LDSC + idx*16) = src[idx];
    }
  }

  // encoder biases from ws
  float bR4[4], bZ4[4], bNi4[4], bNh4[4];
  {
    const float* be = (const float*)(ws + BIASE_OFF) + ((size_t)r*16 + n)*16;
    float4 v0 = *(const float4*)(be);
    float4 v1 = *(const float4*)(be+4);
    float4 v2 = *(const float4*)(be+8);
    float4 v3 = *(const float4*)(be+12);
    bR4[0]=v0.x; bR4[1]=v0.y; bR4[2]=v0.z; bR4[3]=v0.w;
    bZ4[0]=v1.x; bZ4[1]=v1.y; bZ4[2]=v1.z; bZ4[3]=v1.w;
    bNi4[0]=v2.x; bNi4[1]=v2.y; bNi4[2]=v2.z; bNi4[3]=v2.w;
    bNh4[0]=v3.x; bNh4[1]=v3.y; bNh4[2]=v3.z; bNh4[3]=v3.w;
  }

  float hO[4][4];
  #pragma unroll
  for (int ht=0;ht<4;ht++) for (int i=0;i<4;i++) hO[ht][i]=0.f;

  const int ra0 = HB + n*128 + (((  q + n)&7)<<4);
  const int ra1 = HB + n*128 + (((4+q + n)&7)<<4);
  int wa[4];
  #pragma unroll
  for (int i=0;i<4;i++){
    int seq = q*4+i;
    wa[i] = HB + seq*128 + ((((n>>1) + seq)&7)<<4) + ((n&1)<<3);
  }

  // fused pointwise: hn = [En(Ez+h)+(h-Ez)] / [(En+1)(Ez+1)]
  // En=exp2(y), Ez=exp2(-aZ); r-gate: rr=rcp(1+exp2(-aR)); y=aNi+rr*aNh
#define POINTWISE(aR_,aZ_,aNi_,aNh_,HT) \
    _Pragma("unroll") \
    for (int i=0;i<4;i++){ \
      float Er = __builtin_amdgcn_exp2f(-aR_[i]); \
      float rr = __builtin_amdgcn_rcpf(1.f + Er); \
      float y  = aNi_[i] + rr*aNh_[i]; \
      float En = __builtin_amdgcn_exp2f(y); \
      float Ez = __builtin_amdgcn_exp2f(-aZ_[i]); \
      float h  = hO[HT][i]; \
      float e1 = En + 1.f; \
      float den = e1 + e1*Ez; \
      float num = En*(Ez+h) + (h-Ez); \
      float hn = num * __builtin_amdgcn_rcpf(den); \
      hO[HT][i] = hn; \
      if (HT==0)      hsv[i] = hn; \
      else if (HT==1) pk01[i] = pkbf(hsv[i], hn); \
      else if (HT==2) hsv[i] = hn; \
      else            pk23[i] = pkbf(hsv[i], hn); \
    }

  // ---- encoder GRU step ----
  auto step_core = [&](bf16x8 ax){
    bf16x8 a0 = *(const bf16x8*)(LDSC + ra0);
    bf16x8 a1 = *(const bf16x8*)(LDSC + ra1);
    float hsv[4]; u32 pk01[4], pk23[4];
    #pragma unroll
    for (int ht=0; ht<4; ht++){
      bf16x8 bR0 = *(const bf16x8*)(LDSC + LDS_BHE + ((      ht)*64 + l)*16);
      bf16x8 bR1 = *(const bf16x8*)(LDSC + LDS_BHE + ((12  + ht)*64 + l)*16);
      bf16x8 bZ0 = *(const bf16x8*)(LDSC + LDS_BHE + (( 4 + ht)*64 + l)*16);
      bf16x8 bZ1 = *(const bf16x8*)(LDSC + LDS_BHE + ((16  + ht)*64 + l)*16);
      bf16x8 bN0 = *(const bf16x8*)(LDSC + LDS_BHE + (( 8 + ht)*64 + l)*16);
      bf16x8 bN1 = *(const bf16x8*)(LDSC + LDS_BHE + ((20  + ht)*64 + l)*16);
      bf16x8 xR  = *(const bf16x8*)(LDSC + LDS_BXE + ((      ht)*64 + l)*16);
      bf16x8 xZ  = *(const bf16x8*)(LDSC + LDS_BXE + (( 4 + ht)*64 + l)*16);
      bf16x8 xN  = *(const bf16x8*)(LDSC + LDS_BXE + (( 8 + ht)*64 + l)*16);
      f32x4 aR  = f32x4{bR4[ht],bR4[ht],bR4[ht],bR4[ht]};
      f32x4 aZ  = f32x4{bZ4[ht],bZ4[ht],bZ4[ht],bZ4[ht]};
      f32x4 aNi = f32x4{bNi4[ht],bNi4[ht],bNi4[ht],bNi4[ht]};
      f32x4 aNh = f32x4{bNh4[ht],bNh4[ht],bNh4[ht],bNh4[ht]};
      aR = __builtin_amdgcn_mfma_f32_16x16x32_bf16(a0, bR0, aR,0,0,0);
      aR = __builtin_amdgcn_mfma_f32_16x16x32_bf16(a1, bR1, aR,0,0,0);
      aR = __builtin_amdgcn_mfma_f32_16x16x32_bf16(ax, xR,  aR,0,0,0);
      aZ = __builtin_amdgcn_mfma_f32_16x16x32_bf16(a0, bZ0, aZ,0,0,0);
      aZ = __builtin_amdgcn_mfma_f32_16x16x32_bf16(a1, bZ1, aZ,0,0,0);
      aZ = __builtin_amdgcn_mfma_f32_16x16x32_bf16(ax, xZ,  aZ,0,0,0);
      aNh= __builtin_amdgcn_mfma_f32_16x16x32_bf16(a0, bN0, aNh,0,0,0);
      aNh= __builtin_amdgcn_mfma_f32_16x16x32_bf16(a1, bN1, aNh,0,0,0);
      aNi= __builtin_amdgcn_mfma_f32_16x16x32_bf16(ax, xN,  aNi,0,0,0);
      POINTWISE(aR,aZ,aNi,aNh,ht)
    }
    #pragma unroll
    for (int i=0;i<4;i++){
      uint2 wv2; wv2.x = pk01[i]; wv2.y = pk23[i];
      *(uint2*)(LDSC + wa[i]) = wv2;
    }
  };

  // ---------- encoder ----------
  const float* xb = X + (size_t)(seqb + n)*120 + ((q<K)? q:0)*D*8;
  float4 c0 = *(const float4*)(xb);
  float4 c1 = *(const float4*)(xb + 4);
  __syncthreads();   // the ONLY barrier
  #pragma unroll 1
  for (int t=0; t<L; t++){
    int tn = (t+1 < L) ? (t+1) : t;
    float4 n0 = *(const float4*)(xb + tn*8);
    float4 n1 = *(const float4*)(xb + tn*8 + 4);
    BXU a;
    a.u.x = __builtin_amdgcn_perm(__float_as_uint(c0.y), __float_as_uint(c0.x), 0x07060302u);
    a.u.y = __builtin_amdgcn_perm(__float_as_uint(c0.w), __float_as_uint(c0.z), 0x07060302u);
    a.u.z = __builtin_amdgcn_perm(__float_as_uint(c1.y), __float_as_uint(c1.x), 0x07060302u);
    a.u.w = __builtin_amdgcn_perm(__float_as_uint(c1.w), __float_as_uint(c1.z), 0x07060302u);
    step_core(a.v);
    c0 = n0; c1 = n1;
  }

  // ---------- decoder switch: NO barriers (BHD pre-staged) ----------
  {
    const float* bd = (const float*)(ws + BIASD_OFF) + ((size_t)r*16 + n)*16;
    float4 v0 = *(const float4*)(bd);
    float4 v1 = *(const float4*)(bd+4);
    float4 v2 = *(const float4*)(bd+8);
    float4 v3 = *(const float4*)(bd+12);
    bR4[0]=v0.x; bR4[1]=v0.y; bR4[2]=v0.z; bR4[3]=v0.w;
    bZ4[0]=v1.x; bZ4[1]=v1.y; bZ4[2]=v1.z; bZ4[3]=v1.w;
    bNi4[0]=v2.x; bNi4[1]=v2.y; bNi4[2]=v2.z; bNi4[3]=v2.w;
    bNh4[0]=v3.x; bNh4[1]=v3.y; bNh4[2]=v3.z; bNh4[3]=v3.w;
  }
  float dwR[4], dwZ[4], dwN[4];
  {
    const float* dwih = Dwih + r*192;
    #pragma unroll
    for (int ht=0; ht<4; ht++){
      int hid = ht*16 + n;
      dwR[ht] = LOG2E  * dwih[hid];
      dwZ[ht] = LOG2E  * dwih[64+hid];
      dwN[ht] = LOG2E2 * dwih[128+hid];
    }
  }
  float lwr[4];
  #pragma unroll
  for (int ht=0; ht<4; ht++) lwr[ht] = Lw[r*64 + ht*16 + n];
  const float lb_ = Lb[r];
  // wgt for the seq this lane outputs: seq = seqb + q*4 + (n&3)
  const float wgt = ((const float*)(ws + WGT_OFF))[((seqb + q*4 + (n&3)) % NSEQ)*NC + r];
  // lvv[i] = last0 for seq q*4+i
  f32x4 lvv;
  #pragma unroll
  for (int i=0;i<4;i++) lvv[i] = X[(size_t)(seqb + q*4 + i)*120 + 112];

  // ---------- decoder: scalar-x steps, NO barriers, no broadcast ----------
  #pragma unroll 1
  for (int t=0; t<TOUT; t++){
    {
      bf16x8 a0 = *(const bf16x8*)(LDSC + ra0);
      bf16x8 a1 = *(const bf16x8*)(LDSC + ra1);
      float hsv[4]; u32 pk01[4], pk23[4];
      #pragma unroll
      for (int ht=0; ht<4; ht++){
        bf16x8 bR0 = *(const bf16x8*)(LDSC + LDS_BHD + ((      ht)*64 + l)*16);
        bf16x8 bR1 = *(const bf16x8*)(LDSC + LDS_BHD + ((12  + ht)*64 + l)*16);
        bf16x8 bZ0 = *(const bf16x8*)(LDSC + LDS_BHD + (( 4 + ht)*64 + l)*16);
        bf16x8 bZ1 = *(const bf16x8*)(LDSC + LDS_BHD + ((16  + ht)*64 + l)*16);
        bf16x8 bN0 = *(const bf16x8*)(LDSC + LDS_BHD + (( 8 + ht)*64 + l)*16);
        bf16x8 bN1 = *(const bf16x8*)(LDSC + LDS_BHD + ((20  + ht)*64 + l)*16);
        f32x4 aR, aZ, aNi, aNh;
        #pragma unroll
        for (int i=0;i<4;i++){
          aR[i]  = bR4[ht]  + lvv[i]*dwR[ht];
          aZ[i]  = bZ4[ht]  + lvv[i]*dwZ[ht];
          aNi[i] = bNi4[ht] + lvv[i]*dwN[ht];
          aNh[i] = bNh4[ht];
        }
        aR = __builtin_amdgcn_mfma_f32_16x16x32_bf16(a0, bR0, aR,0,0,0);
        aR = __builtin_amdgcn_mfma_f32_16x16x32_bf16(a1, bR1, aR,0,0,0);
        aZ = __builtin_amdgcn_mfma_f32_16x16x32_bf16(a0, bZ0, aZ,0,0,0);
        aZ = __builtin_amdgcn_mfma_f32_16x16x32_bf16(a1, bZ1, aZ,0,0,0);
        aNh= __builtin_amdgcn_mfma_f32_16x16x32_bf16(a0, bN0, aNh,0,0,0);
        aNh= __builtin_amdgcn_mfma_f32_16x16x32_bf16(a1, bN1, aNh,0,0,0);
        POINTWISE(aR,aZ,aNi,aNh,ht)
      }
      #pragma unroll
      for (int i=0;i<4;i++){
        uint2 wv2; wv2.x = pk01[i]; wv2.y = pk23[i];
        *(uint2*)(LDSC + wa[i]) = wv2;
      }
    }
    float p[4];
    #pragma unroll
    for (int i=0;i<4;i++)
      p[i] = hO[0][i]*lwr[0] + hO[1][i]*lwr[1] + hO[2][i]*lwr[2] + hO[3][i]*lwr[3];
    #pragma unroll
    for (int m=1; m<16; m<<=1){
      #pragma unroll
      for (int i=0;i<4;i++) p[i] += __shfl_xor(p[i], m, 64);
    }
    // lane(q,n) now holds v for its 4 seqs
    #pragma unroll
    for (int i=0;i<4;i++) lvv[i] = p[i] + lb_;
    if (n < 4){
      float vout = (n&2) ? ((n&1)? lvv[3] : lvv[2]) : ((n&1)? lvv[1] : lvv[0]);
      atomicAdd(out + (size_t)(seqb + q*4 + n)*TOUT + t, wgt*vout);
    }
  }
}

extern "C" void kernel_launch(void* const* d_in, const int* in_sizes, int n_in,
                              void* d_out, int out_size, void* d_ws, size_t ws_size,
                              hipStream_t stream)
{
  float* out = (float*)d_out;
  hipMemsetAsync(out, 0, (size_t)out_size*sizeof(float), stream);

  prep_kernel<<<dim3(NC), 512, 0, stream>>>(
    (const float*)d_in[2], (const float*)d_in[3], (const float*)d_in[4],
    (const float*)d_in[5],
    (const float*)d_in[6], (const float*)d_in[7], (const float*)d_in[8], (const float*)d_in[9],
    (const float*)d_in[10],(const float*)d_in[11],(const float*)d_in[12],(const float*)d_in[13],
    (const float*)d_in[16],
    (char*)d_ws);

  dim3 g(NSEQ*64/128, NC);
  rnn_kernel<<<g, 512, 0, stream>>>(
    (const float*)d_in[1],
    (const float*)d_in[10],
    (const float*)d_in[14], (const float*)d_in[15],
    (const char*)d_ws,
    out);
}